// Round 1
// baseline (31.389 us; speedup 1.0000x reference)
//
#include <hip/hip_runtime.h>

// Problem: x[4096,4096] f32, weight[4096,4096] f32
// out[b] = (2.0 * 0.5) * sum_i x[b,i] * (sum_j weight[j,i])
// Factorized: column-sum of weight, then per-row dot. Memory-bound.

#define BATCH 4096
#define ISZ   4096   // INPUT_SIZE (columns of weight, inner dim)
#define HSZ   4096   // HIDDEN_SIZE (rows of weight)
#define ROW_CHUNKS 64
#define ROWS_PER_CHUNK (HSZ / ROW_CHUNKS)   // 64
#define COL4 (ISZ / 4)                       // 1024 float4 columns
#define SCALE 1.0f                           // SCALE_DIV * SCALING_FACTOR

// Kernel 1: partial column sums of weight.
// grid = (COL4/256, ROW_CHUNKS) = (4, 64), block = 256
// part[chunk][col] = sum of weight[row0..row0+64)[col]
__global__ __launch_bounds__(256) void colsum_partial(
    const float* __restrict__ w, float* __restrict__ part) {
    const int col4  = blockIdx.x * 256 + threadIdx.x;   // float4 column index
    const int chunk = blockIdx.y;
    const float4* w4 = (const float4*)w;
    const size_t row0 = (size_t)chunk * ROWS_PER_CHUNK;
    float4 acc = make_float4(0.f, 0.f, 0.f, 0.f);
    #pragma unroll 4
    for (int r = 0; r < ROWS_PER_CHUNK; ++r) {
        float4 v = w4[(row0 + r) * COL4 + col4];
        acc.x += v.x; acc.y += v.y; acc.z += v.z; acc.w += v.w;
    }
    ((float4*)part)[(size_t)chunk * COL4 + col4] = acc;
}

// Kernel 2: reduce the ROW_CHUNKS partials per column -> wsum[4096].
// grid = (COL4/256) = 4, block = 256
__global__ __launch_bounds__(256) void colsum_finish(
    const float* __restrict__ part, float* __restrict__ wsum) {
    const int col4 = blockIdx.x * 256 + threadIdx.x;
    const float4* p4 = (const float4*)part;
    float4 acc = make_float4(0.f, 0.f, 0.f, 0.f);
    #pragma unroll 8
    for (int c = 0; c < ROW_CHUNKS; ++c) {
        float4 v = p4[(size_t)c * COL4 + col4];
        acc.x += v.x; acc.y += v.y; acc.z += v.z; acc.w += v.w;
    }
    ((float4*)wsum)[col4] = acc;
}

// Kernel 3: out[b] = SCALE * dot(x[b,:], wsum)
// grid = BATCH, block = 256 (4 waves). Each thread: 4 x float4.
__global__ __launch_bounds__(256) void rowdot(
    const float* __restrict__ x, const float* __restrict__ wsum,
    float* __restrict__ out) {
    const int b   = blockIdx.x;
    const int tid = threadIdx.x;
    const float4* x4 = (const float4*)(x + (size_t)b * ISZ);
    const float4* s4 = (const float4*)wsum;
    float acc = 0.f;
    #pragma unroll
    for (int it = 0; it < COL4 / 256; ++it) {   // 4 iterations
        const int idx = it * 256 + tid;
        float4 xv = x4[idx];
        float4 sv = s4[idx];
        acc += xv.x * sv.x + xv.y * sv.y + xv.z * sv.z + xv.w * sv.w;
    }
    // wave64 shuffle reduce
    #pragma unroll
    for (int off = 32; off > 0; off >>= 1)
        acc += __shfl_down(acc, off, 64);
    __shared__ float red[4];
    const int wave = tid >> 6;
    if ((tid & 63) == 0) red[wave] = acc;
    __syncthreads();
    if (tid == 0) {
        out[b] = SCALE * (red[0] + red[1] + red[2] + red[3]);
    }
}

extern "C" void kernel_launch(void* const* d_in, const int* in_sizes, int n_in,
                              void* d_out, int out_size, void* d_ws, size_t ws_size,
                              hipStream_t stream) {
    const float* x = (const float*)d_in[0];       // [BATCH, ISZ]
    const float* w = (const float*)d_in[1];       // [HSZ, ISZ]
    float* out = (float*)d_out;                   // [BATCH]

    float* part = (float*)d_ws;                               // ROW_CHUNKS*ISZ f32 = 1 MiB
    float* wsum = (float*)d_ws + (size_t)ROW_CHUNKS * ISZ;    // ISZ f32 = 16 KiB

    colsum_partial<<<dim3(COL4 / 256, ROW_CHUNKS), 256, 0, stream>>>(w, part);
    colsum_finish<<<dim3(COL4 / 256), 256, 0, stream>>>(part, wsum);
    rowdot<<<dim3(BATCH), 256, 0, stream>>>(x, wsum, out);
}